// Round 7
// baseline (11266.096 us; speedup 1.0000x reference)
//
#include <hip/hip_runtime.h>

#define T_STEPS 8192
#define BATCH   128
#define HID     128

typedef float v2f __attribute__((ext_vector_type(2)));

// tanh(z) = sign(z) * (1 - e^{-2|z|}) / (1 + e^{-2|z|})  -- no overflow path
__device__ __forceinline__ float fast_tanh(float z) {
    float az = fabsf(z);
    float e  = __expf(-2.0f * az);
    float r  = __fdividef(1.0f - e, 1.0f + e);
    return copysignf(r, z);
}

// wave64 sum via DPP (VALU-only, 6 dependent adds), broadcast from lane 63.
__device__ __forceinline__ float wave64_sum(float x) {
#define DPP_ADD(ctrl) do {                                                        \
        int t_ = __builtin_amdgcn_update_dpp(0, __builtin_bit_cast(int, x),       \
                                             (ctrl), 0xf, 0xf, false);            \
        x += __builtin_bit_cast(float, t_); } while (0)
    DPP_ADD(0x111);  // row_shr:1
    DPP_ADD(0x112);  // row_shr:2
    DPP_ADD(0x114);  // row_shr:4
    DPP_ADD(0x118);  // row_shr:8
    DPP_ADD(0x142);  // row_bcast:15
    DPP_ADD(0x143);  // row_bcast:31 -> lane 63 holds full sum
#undef DPP_ADD
    int s_ = __builtin_amdgcn_readlane(__builtin_bit_cast(int, x), 63);
    return __builtin_bit_cast(float, s_);
}

__device__ __forceinline__ float bcast_lane(float v, int l) {
    int r = __builtin_amdgcn_readlane(__builtin_bit_cast(int, v), l);
    return __builtin_bit_cast(float, r);
}

#define FORALL32(M) M(0) M(1) M(2) M(3) M(4) M(5) M(6) M(7) \
                    M(8) M(9) M(10) M(11) M(12) M(13) M(14) M(15) \
                    M(16) M(17) M(18) M(19) M(20) M(21) M(22) M(23) \
                    M(24) M(25) M(26) M(27) M(28) M(29) M(30) M(31)

// ONE WAVE per batch element. Zero s_barrier in the whole kernel: the only
// sync is same-wave lgkmcnt on the h1 LDS round-trip. R6 falsified the
// LDS-pipe theory; the ~850 unexplained cyc/step all sat in inter-wave
// coordination (2x barrier + specialized-wave arrival spread) -- removed
// wholesale here. launch_bounds(64,1): VGPR budget 512, so the 256-float
// W2 working set (2 columns/lane, packed as 128 v2f for v_pk_fma_f32)
// finally fits in registers -- the R1-R3 blocker was the occupancy cap.
__global__ __launch_bounds__(64, 1) void odenet_scan(
    const float* __restrict__ x,
    const float* __restrict__ W1, const float* __restrict__ b1,
    const float* __restrict__ W2, const float* __restrict__ b2,
    const float* __restrict__ W3, const float* __restrict__ b3,
    float* __restrict__ out) {

    const int b = blockIdx.x;          // batch element
    const int l = threadIdx.x;         // lane; owns hidden units l and l+64

    __shared__ __align__(16) float h1buf[HID];

    // ---- W2 working set: columns l and l+64, packed in pairs along k ----
    const float* colA = W2 + l;        // column l      (row stride HID)
    const float* colB = W2 + l + 64;   // column l + 64
#define DECLW(i)                                                                  \
    v2f waA##i = {colA[(4*i+0)*HID], colA[(4*i+1)*HID]},                          \
        waB##i = {colA[(4*i+2)*HID], colA[(4*i+3)*HID]},                          \
        wbA##i = {colB[(4*i+0)*HID], colB[(4*i+1)*HID]},                          \
        wbB##i = {colB[(4*i+2)*HID], colB[(4*i+3)*HID]};
    FORALL32(DECLW)
#undef DECLW
#define PINW(i) asm("" : "+v"(waA##i), "+v"(waB##i), "+v"(wbA##i), "+v"(wbB##i));
    FORALL32(PINW)
#undef PINW

    const float w1xa = W1[l],      w1ya = W1[HID + l],      b1a = b1[l];
    const float w1xb = W1[l + 64], w1yb = W1[HID + l + 64], b1b = b1[l + 64];
    const float b2a = b2[l], b2b = b2[l + 64];
    const float w3a = W3[l], w3b = W3[l + 64];
    const float b3v = b3[0];

    float y    = 0.0f;
    float xbuf = 0.0f;   // lane l holds x[(tblk+l)*B + b]
    float ybuf = 0.0f;   // lane l holds y_{tblk+l+1}
    if (l == 0) out[b] = 0.0f;         // y_0 = 0

    const float4* h4 = (const float4*)h1buf;

    for (int t = 0; t < T_STEPS - 1; ++t) {
        const int tm = t & 63;
        if (tm == 0)                               // one x block per 64 steps
            xbuf = x[(t + l) * BATCH + b];
        float xv = bcast_lane(xbuf, tm);           // uniform (SGPR)

        // ---- layer 1: this lane's two h1 entries -> LDS (ds_write2) ----
        h1buf[l]      = fast_tanh(fmaf(xv, w1xa, fmaf(y, w1ya, b1a)));
        h1buf[l + 64] = fast_tanh(fmaf(xv, w1xb, fmaf(y, w1yb, b1b)));
        // same-wave RAW: compiler inserts lgkmcnt wait, NO barrier needed

        // ---- layer 2: 128 v_pk_fma_f32 against broadcast b128 reads ----
        v2f accaA = {0.f, 0.f}, accaB = {0.f, 0.f};
        v2f accbA = {0.f, 0.f}, accbB = {0.f, 0.f};
#define FMAQ(i) { float4 q = h4[i];                                               \
        v2f hlo = {q.x, q.y}, hhi = {q.z, q.w};                                   \
        accaA += waA##i * hlo;  accaB += waB##i * hhi;                            \
        accbA += wbA##i * hlo;  accbB += wbB##i * hhi; }
        FORALL32(FMAQ)
#undef FMAQ
        float h2a = fast_tanh((accaA.x + accaA.y) + (accaB.x + accaB.y) + b2a);
        float h2b = fast_tanh((accbA.x + accbA.y) + (accbB.x + accbB.y) + b2b);

        // ---- layer 3 + wave reduction ----
        float p = fmaf(w3a, h2a, w3b * h2b);
        y += wave64_sum(p) + b3v;                  // DT = 1.0

        // capture y_{t+1} in lane tm; flush 64 states once per 64 steps
        ybuf = (l == tm) ? y : ybuf;
        if (tm == 63)
            out[(t - 62 + l) * BATCH + b] = ybuf;
    }
    // tail: t=8128..8190 captured y_8129..y_8191 in lanes 0..62
    if (l < 63)
        out[(T_STEPS - 63 + l) * BATCH + b] = ybuf;
}

extern "C" void kernel_launch(void* const* d_in, const int* in_sizes, int n_in,
                              void* d_out, int out_size, void* d_ws, size_t ws_size,
                              hipStream_t stream) {
    const float* x  = (const float*)d_in[0];
    const float* W1 = (const float*)d_in[1];
    const float* b1 = (const float*)d_in[2];
    const float* W2 = (const float*)d_in[3];
    const float* b2 = (const float*)d_in[4];
    const float* W3 = (const float*)d_in[5];
    const float* b3 = (const float*)d_in[6];

    odenet_scan<<<dim3(BATCH), dim3(64), 0, stream>>>(
        x, W1, b1, W2, b2, W3, b3, (float*)d_out);
}

// Round 8
// 4812.870 us; speedup vs baseline: 2.3408x; 2.3408x over previous
//
#include <hip/hip_runtime.h>

#define T_STEPS 8192
#define BATCH   128
#define HID     128
#define SPLIT   4
#define NTHR    (HID * SPLIT)     // 512 threads = 8 waves

// tanh(z) = sign(z) * (1 - e^{-2|z|}) / (1 + e^{-2|z|})  -- no overflow path
__device__ __forceinline__ float fast_tanh(float z) {
    float az = fabsf(z);
    float e  = __expf(-2.0f * az);
    float r  = __fdividef(1.0f - e, 1.0f + e);
    return copysignf(r, z);
}

// wave64 sum via DPP (VALU-only, 6 dependent adds), broadcast from lane 63.
__device__ __forceinline__ float wave64_sum(float x) {
#define DPP_ADD(ctrl) do {                                                        \
        int t_ = __builtin_amdgcn_update_dpp(0, __builtin_bit_cast(int, x),       \
                                             (ctrl), 0xf, 0xf, false);            \
        x += __builtin_bit_cast(float, t_); } while (0)
    DPP_ADD(0x111);  // row_shr:1
    DPP_ADD(0x112);  // row_shr:2
    DPP_ADD(0x114);  // row_shr:4
    DPP_ADD(0x118);  // row_shr:8
    DPP_ADD(0x142);  // row_bcast:15
    DPP_ADD(0x143);  // row_bcast:31 -> lane 63 holds full sum
#undef DPP_ADD
    int s_ = __builtin_amdgcn_readlane(__builtin_bit_cast(int, x), 63);
    return __builtin_bit_cast(float, s_);
}

__device__ __forceinline__ float bcast_lane(float v, int l) {
    int r = __builtin_amdgcn_readlane(__builtin_bit_cast(int, v), l);
    return __builtin_bit_cast(float, r);
}

// R8: ONE symmetric barrier per step. All 8 waves run identical code:
//  - h1 chunk computed IN-WAVE (x,y are wave-replicated) -> no LDS for h1,
//    no phase-A specialization, no barrier #1
//  - partials -> pbuf[t&1] (double-buffered -> WAR barrier #2 eliminated)
//  - ONE __syncthreads, then phase C redundantly in every wave -> each wave
//    owns its y copy (bit-identical across waves: same inputs, same order)
// Register/thread mapping unchanged from R6 (proven: no per-step W2 refetch).
__global__ __launch_bounds__(NTHR, 2) void odenet_scan(
    const float* __restrict__ x,
    const float* __restrict__ W1, const float* __restrict__ b1,
    const float* __restrict__ W2, const float* __restrict__ b2,
    const float* __restrict__ W3, const float* __restrict__ b3,
    float* __restrict__ out) {

    const int b    = blockIdx.x;       // batch element
    const int tid  = threadIdx.x;
    const int s    = tid >> 7;         // k-split index 0..3 (uniform per wave-pair)
    const int j    = tid & (HID - 1);  // output hidden unit 0..127
    const int lane = tid & 63;
    const int k    = (s << 5) | (lane & 31);   // h1 index this lane computes

    __shared__ __align__(16) float pbuf[2][NTHR];  // [parity][s*HID + j]

    // ---- W2 fragment: rows [32s, 32s+32) of column j, 32 scalars ----
    const float* col = W2 + j;         // column j, row stride HID
    const int kb = 32 * s;
#define LW(kk) col[(kb + (kk)) * HID]
    float w00 = LW( 0), w01 = LW( 1), w02 = LW( 2), w03 = LW( 3);
    float w04 = LW( 4), w05 = LW( 5), w06 = LW( 6), w07 = LW( 7);
    float w08 = LW( 8), w09 = LW( 9), w10_ = LW(10), w11_ = LW(11);
    float w12 = LW(12), w13 = LW(13), w14 = LW(14), w15 = LW(15);
    float w16 = LW(16), w17 = LW(17), w18 = LW(18), w19 = LW(19);
    float w20 = LW(20), w21 = LW(21), w22 = LW(22), w23 = LW(23);
    float w24 = LW(24), w25 = LW(25), w26 = LW(26), w27 = LW(27);
    float w28 = LW(28), w29 = LW(29), w30 = LW(30), w31 = LW(31);
#undef LW
    // layer-1 weights for the h1 unit k this lane computes (not j!)
    float w1xk = W1[k], w1yk = W1[HID + k], b1k = b1[k];
    float b2a = b2[lane], b2b = b2[lane + 64];
    float w3a = W3[lane], w3b = W3[lane + 64];
    float b3v = b3[0];

#define PIN8(a,b_,c,d,e,f,g,h) asm volatile("" : "+v"(a),"+v"(b_),"+v"(c),      \
        "+v"(d),"+v"(e),"+v"(f),"+v"(g),"+v"(h))
    PIN8(w00, w01, w02, w03, w04, w05, w06, w07);
    PIN8(w08, w09, w10_, w11_, w12, w13, w14, w15);
    PIN8(w16, w17, w18, w19, w20, w21, w22, w23);
    PIN8(w24, w25, w26, w27, w28, w29, w30, w31);
    PIN8(w1xk, w1yk, b1k, b2a, b2b, w3a, w3b, b3v);
#undef PIN8

    float y    = 0.0f;
    float xbuf = 0.0f;   // per wave: lane l holds x[(tblk+l)*B + b]
    float ybuf = 0.0f;   // wave 0: lane l holds y_{tblk+l+1}
    if (tid == 0) out[b] = 0.0f;       // y_0 = 0

    for (int t = 0; t < T_STEPS - 1; ++t) {
        const int tm = t & 63;
        if (tm == 0)                               // one x block per 64 steps
            xbuf = x[(t + lane) * BATCH + b];      // all waves: same addrs, L1-served
        float xv = bcast_lane(xbuf, tm);           // uniform (SGPR)

        // ---- layer 1, in-wave: lane computes h1[k] for its own chunk ----
        float h1v = fast_tanh(fmaf(xv, w1xk, fmaf(y, w1yk, b1k)));

        // ---- layer 2 partial: 32 readlane -> SGPR, FMA with SGPR operand ----
        float a0 = 0.f, a1 = 0.f, a2 = 0.f, a3 = 0.f;
#define H1(m) __builtin_bit_cast(float, __builtin_amdgcn_readlane(              \
                                     __builtin_bit_cast(int, h1v), (m)))
        a0 = fmaf(H1( 0), w00, a0);  a1 = fmaf(H1( 1), w01, a1);
        a2 = fmaf(H1( 2), w02, a2);  a3 = fmaf(H1( 3), w03, a3);
        a0 = fmaf(H1( 4), w04, a0);  a1 = fmaf(H1( 5), w05, a1);
        a2 = fmaf(H1( 6), w06, a2);  a3 = fmaf(H1( 7), w07, a3);
        a0 = fmaf(H1( 8), w08, a0);  a1 = fmaf(H1( 9), w09, a1);
        a2 = fmaf(H1(10), w10_, a2); a3 = fmaf(H1(11), w11_, a3);
        a0 = fmaf(H1(12), w12, a0);  a1 = fmaf(H1(13), w13, a1);
        a2 = fmaf(H1(14), w14, a2);  a3 = fmaf(H1(15), w15, a3);
        a0 = fmaf(H1(16), w16, a0);  a1 = fmaf(H1(17), w17, a1);
        a2 = fmaf(H1(18), w18, a2);  a3 = fmaf(H1(19), w19, a3);
        a0 = fmaf(H1(20), w20, a0);  a1 = fmaf(H1(21), w21, a1);
        a2 = fmaf(H1(22), w22, a2);  a3 = fmaf(H1(23), w23, a3);
        a0 = fmaf(H1(24), w24, a0);  a1 = fmaf(H1(25), w25, a1);
        a2 = fmaf(H1(26), w26, a2);  a3 = fmaf(H1(27), w27, a3);
        a0 = fmaf(H1(28), w28, a0);  a1 = fmaf(H1(29), w29, a1);
        a2 = fmaf(H1(30), w30, a2);  a3 = fmaf(H1(31), w31, a3);
#undef H1
        float* pb = pbuf[t & 1];
        pb[s * HID + j] = (a0 + a1) + (a2 + a3);

        __syncthreads();   // the ONLY barrier: partials visible to all waves

        // ---- phase C, redundant in every wave (identical result bits) ----
        float sa = pb[0 * HID + lane]      + pb[1 * HID + lane]
                 + pb[2 * HID + lane]      + pb[3 * HID + lane];
        float sb = pb[0 * HID + lane + 64] + pb[1 * HID + lane + 64]
                 + pb[2 * HID + lane + 64] + pb[3 * HID + lane + 64];
        float c = fmaf(w3a, fast_tanh(sa + b2a), w3b * fast_tanh(sb + b2b));
        y += wave64_sum(c) + b3v;                  // DT = 1.0

        // capture + batched store (wave 0 only; branch is wave-uniform)
        if (tid < 64) {
            ybuf = (lane == tm) ? y : ybuf;
            if (tm == 63)
                out[(t - 62 + lane) * BATCH + b] = ybuf;
        }
    }
    // tail: t=8128..8190 captured y_8129..y_8191 in lanes 0..62 of wave 0
    if (tid < 63)
        out[(T_STEPS - 63 + lane) * BATCH + b] = ybuf;
}

extern "C" void kernel_launch(void* const* d_in, const int* in_sizes, int n_in,
                              void* d_out, int out_size, void* d_ws, size_t ws_size,
                              hipStream_t stream) {
    const float* x  = (const float*)d_in[0];
    const float* W1 = (const float*)d_in[1];
    const float* b1 = (const float*)d_in[2];
    const float* W2 = (const float*)d_in[3];
    const float* b2 = (const float*)d_in[4];
    const float* W3 = (const float*)d_in[5];
    const float* b3 = (const float*)d_in[6];

    odenet_scan<<<dim3(BATCH), dim3(NTHR), 0, stream>>>(
        x, W1, b1, W2, b2, W3, b3, (float*)d_out);
}